// Round 2
// baseline (354.679 us; speedup 1.0000x reference)
//
#include <hip/hip_runtime.h>
#include <math.h>

#define NROWS 32768
#define DDIM  1024
#define NEXP  64
#define BM    64
#define BK    64
#define LPAD  68                 // padded row stride (floats) -> conflict-free
#define NCHUNK (DDIM / BK)       // 16
#define TILEF (BM * LPAD)        // 4352 floats per [64][68] region
#define EPSF  1e-9f

// ---------------------------------------------------------------------------
// Fused router: GEMM (x @ gate_w^T) + softmax + top-2 + aux accumulation.
// grid = 512 (64 rows each), block = 256 (4 waves, wave-level split-K).
// 2-phase pipeline: global loads for chunk t+1 issued BEFORE computing chunk
// t (load latency hidden under ~2k cycles of FMA), ds_write to the alternate
// LDS buffer after compute, ONE barrier per chunk (no vmcnt drain stall).
// ---------------------------------------------------------------------------
__global__ __launch_bounds__(256, 2) void moe_router_kernel(
    const float* __restrict__ x, const float* __restrict__ gw,
    float* __restrict__ out, float* __restrict__ meanacc)
{
    extern __shared__ float smem[];          // 4 x [64][68] tile regions
    float* const xs0 = smem;
    float* const xs1 = smem + TILEF;
    float* const ws0 = smem + 2 * TILEF;
    float* const ws1 = smem + 3 * TILEF;

    const int t    = threadIdx.x;
    const int wave = t >> 6;
    const int lane = t & 63;
    const int tr   = lane >> 3;   // row group 0..7   (rows  tr + 8*i)
    const int tc   = lane & 7;    // expert group 0..7 (experts tc + 8*j)
    const int row0 = blockIdx.x * BM;

    // staging map: thread covers f4 slots {t + 256*s}: row = strow+16s, col = stcol
    const int strow = t >> 4;
    const int stcol = (t & 15) << 2;

    const float* xg = x  + (size_t)(row0 + strow) * DDIM + stcol;
    const float* wg = gw + (size_t)strow * DDIM + stcol;

    float acc[8][8];
    #pragma unroll
    for (int i = 0; i < 8; ++i)
        #pragma unroll
        for (int j = 0; j < 8; ++j) acc[i][j] = 0.0f;

    float4 xr[4], wr[4];

    // ---- prologue: stage chunk 0 ------------------------------------------
    #pragma unroll
    for (int s = 0; s < 4; ++s) {
        xr[s] = *reinterpret_cast<const float4*>(xg + (size_t)(16 * s) * DDIM);
        wr[s] = *reinterpret_cast<const float4*>(wg + (size_t)(16 * s) * DDIM);
    }
    #pragma unroll
    for (int s = 0; s < 4; ++s) {
        *reinterpret_cast<float4*>(xs0 + (strow + 16 * s) * LPAD + stcol) = xr[s];
        *reinterpret_cast<float4*>(ws0 + (strow + 16 * s) * LPAD + stcol) = wr[s];
    }
    __syncthreads();

    // ---- main pipelined K loop --------------------------------------------
    for (int t0 = 0; t0 < NCHUNK; ++t0) {
        const float* xb = (t0 & 1) ? xs1 : xs0;
        const float* wb = (t0 & 1) ? ws1 : ws0;
        float* xn = (t0 & 1) ? xs0 : xs1;
        float* wn = (t0 & 1) ? ws0 : ws1;
        const bool more = (t0 + 1 < NCHUNK);

        // issue next chunk's global loads early (latency hides under FMAs)
        if (more) {
            const int k0 = (t0 + 1) * BK;
            #pragma unroll
            for (int s = 0; s < 4; ++s) {
                xr[s] = *reinterpret_cast<const float4*>(xg + (size_t)(16 * s) * DDIM + k0);
                wr[s] = *reinterpret_cast<const float4*>(wg + (size_t)(16 * s) * DDIM + k0);
            }
        }

        // compute this wave's K-slice (16 of the 64 k's) of the current chunk
        #pragma unroll
        for (int s2 = 0; s2 < 4; ++s2) {
            const int c = (wave * 4 + s2) * 4;
            float4 xv[8], wv[8];
            #pragma unroll
            for (int i = 0; i < 8; ++i)
                xv[i] = *reinterpret_cast<const float4*>(xb + (tr + 8 * i) * LPAD + c);
            #pragma unroll
            for (int j = 0; j < 8; ++j)
                wv[j] = *reinterpret_cast<const float4*>(wb + (tc + 8 * j) * LPAD + c);
            #pragma unroll
            for (int i = 0; i < 8; ++i)
                #pragma unroll
                for (int j = 0; j < 8; ++j) {
                    acc[i][j] += xv[i].x * wv[j].x;
                    acc[i][j] += xv[i].y * wv[j].y;
                    acc[i][j] += xv[i].z * wv[j].z;
                    acc[i][j] += xv[i].w * wv[j].w;
                }
        }

        // write prefetched chunk into the other buffer (vmcnt waits here only)
        if (more) {
            #pragma unroll
            for (int s = 0; s < 4; ++s) {
                *reinterpret_cast<float4*>(xn + (strow + 16 * s) * LPAD + stcol) = xr[s];
                *reinterpret_cast<float4*>(wn + (strow + 16 * s) * LPAD + stcol) = wr[s];
            }
        }
        __syncthreads();
    }

    // ---- cross-wave reduction of split-K partials (tree through LDS) ------
    float* redA = xs0;
    float* redB = xs1;
    if (wave == 1) {
        #pragma unroll
        for (int i = 0; i < 8; ++i)
            #pragma unroll
            for (int j = 0; j < 8; ++j)
                redA[(tr + 8 * i) * LPAD + tc + 8 * j] = acc[i][j];
    } else if (wave == 3) {
        #pragma unroll
        for (int i = 0; i < 8; ++i)
            #pragma unroll
            for (int j = 0; j < 8; ++j)
                redB[(tr + 8 * i) * LPAD + tc + 8 * j] = acc[i][j];
    }
    __syncthreads();
    if (wave == 0) {
        #pragma unroll
        for (int i = 0; i < 8; ++i)
            #pragma unroll
            for (int j = 0; j < 8; ++j)
                acc[i][j] += redA[(tr + 8 * i) * LPAD + tc + 8 * j];
    } else if (wave == 2) {
        #pragma unroll
        for (int i = 0; i < 8; ++i)
            #pragma unroll
            for (int j = 0; j < 8; ++j)
                acc[i][j] += redB[(tr + 8 * i) * LPAD + tc + 8 * j];
    }
    __syncthreads();
    if (wave == 2) {
        #pragma unroll
        for (int i = 0; i < 8; ++i)
            #pragma unroll
            for (int j = 0; j < 8; ++j)
                redA[(tr + 8 * i) * LPAD + tc + 8 * j] = acc[i][j];
    }
    __syncthreads();

    if (wave != 0) return;   // no more barriers below

    #pragma unroll
    for (int i = 0; i < 8; ++i)
        #pragma unroll
        for (int j = 0; j < 8; ++j)
            acc[i][j] += redA[(tr + 8 * i) * LPAD + tc + 8 * j];

    // ---- fused epilogue: softmax + top-2 + aux accumulation ---------------
    float auxacc[8];
    #pragma unroll
    for (int j = 0; j < 8; ++j) auxacc[j] = 0.0f;

    #pragma unroll
    for (int i = 0; i < 8; ++i) {
        // local stable top-2 over this lane's 8 experts
        float v1 = -3.4e38f, v2 = -3.4e38f;
        int   e1 = 1 << 30,  e2 = 1 << 30;
        #pragma unroll
        for (int j = 0; j < 8; ++j) {
            float v = acc[i][j];
            int   e = tc + 8 * j;
            if (v > v1 || (v == v1 && e < e1)) { v2 = v1; e2 = e1; v1 = v; e1 = e; }
            else if (v > v2 || (v == v2 && e < e2)) { v2 = v; e2 = e; }
        }
        // merge across the 8 lanes holding this row (stable, lower index wins)
        #pragma unroll
        for (int m = 1; m <= 4; m <<= 1) {
            float o1 = __shfl_xor(v1, m); int oe1 = __shfl_xor(e1, m);
            float o2 = __shfl_xor(v2, m); int oe2 = __shfl_xor(e2, m);
            bool aFirst = (v1 > o1) || (v1 == o1 && e1 < oe1);
            float n1, n2; int ne1, ne2;
            if (aFirst) {
                n1 = v1; ne1 = e1;
                bool sA = (v2 > o1) || (v2 == o1 && e2 < oe1);
                if (sA) { n2 = v2; ne2 = e2; } else { n2 = o1; ne2 = oe1; }
            } else {
                n1 = o1; ne1 = oe1;
                bool sB = (o2 > v1) || (o2 == v1 && oe2 < e1);
                if (sB) { n2 = o2; ne2 = oe2; } else { n2 = v1; ne2 = e1; }
            }
            v1 = n1; e1 = ne1; v2 = n2; e2 = ne2;
        }
        const float mx = v1;  // global row max

        float p[8];
        float sloc = 0.0f;
        #pragma unroll
        for (int j = 0; j < 8; ++j) { p[j] = expf(acc[i][j] - mx); sloc += p[j]; }
        float S = sloc;
        #pragma unroll
        for (int m = 1; m <= 4; m <<= 1) S += __shfl_xor(S, m);
        const float invS = 1.0f / S;

        const float p1 = expf(v1 - mx) * invS;   // = invS (v1 == mx)
        const float p2 = expf(v2 - mx) * invS;
        const float dn = p1 + p2 + EPSF;
        const float w1 = p1 / dn;
        const float w2 = p2 / dn;

        if (tc == 0) {
            const int r = row0 + tr + 8 * i;
            out[2 * r]                 = w1;
            out[2 * r + 1]             = w2;
            out[2 * NROWS + 2 * r]     = (float)e1;
            out[2 * NROWS + 2 * r + 1] = (float)e2;
        }
        #pragma unroll
        for (int j = 0; j < 8; ++j) auxacc[j] += p[j] * invS;
    }

    // reduce aux probs across the 8 row-groups (lanes differing in tr bits)
    #pragma unroll
    for (int m = 8; m <= 32; m <<= 1)
        #pragma unroll
        for (int j = 0; j < 8; ++j) auxacc[j] += __shfl_xor(auxacc[j], m);
    if (tr == 0) {
        #pragma unroll
        for (int j = 0; j < 8; ++j)
            atomicAdd(&meanacc[tc + 8 * j], auxacc[j]);
    }
}

__global__ void zero_ws_kernel(float* __restrict__ m)
{
    m[threadIdx.x] = 0.0f;
}

__global__ void aux_loss_kernel(const float* __restrict__ m,
                                float* __restrict__ out)
{
    const int e = threadIdx.x;           // 64 threads = 1 wave
    float mean = m[e] * (1.0f / (float)NROWS);
    float v = mean * logf(mean + EPSF);
    #pragma unroll
    for (int k = 1; k <= 32; k <<= 1) v += __shfl_xor(v, k);
    if (e == 0) out[4 * NROWS] = v;      // index 131072
}

extern "C" void kernel_launch(void* const* d_in, const int* in_sizes, int n_in,
                              void* d_out, int out_size, void* d_ws, size_t ws_size,
                              hipStream_t stream)
{
    const float* x   = (const float*)d_in[0];
    const float* gw  = (const float*)d_in[1];
    float* out       = (float*)d_out;
    float* meanacc   = (float*)d_ws;

    const size_t lds_bytes = 4 * TILEF * sizeof(float);   // 69632 B dynamic LDS

    hipLaunchKernelGGL(zero_ws_kernel, dim3(1), dim3(NEXP), 0, stream, meanacc);
    hipLaunchKernelGGL(moe_router_kernel, dim3(NROWS / BM), dim3(256), lds_bytes,
                       stream, x, gw, out, meanacc);
    hipLaunchKernelGGL(aux_loss_kernel, dim3(1), dim3(NEXP), 0, stream,
                       meanacc, out);
}

// Round 4
// 104.831 us; speedup vs baseline: 3.3833x; 3.3833x over previous
//
#include <hip/hip_runtime.h>
#include <math.h>

#define NROWS 32768
#define DDIM  1024
#define NEXP  64
#define BM    64
#define BK    64
#define LPAD  68                  // padded row stride (floats) -> conflict-free
#define TILEF (BM * LPAD)         // 4352 floats per [64][68] region
#define EPSF  1e-9f

// ---------------------------------------------------------------------------
// Fused router: GEMM (x @ gate_w^T) + softmax + top-2 + aux accumulation.
// grid = 512 (64 rows each), block = 512 threads (8 waves, 8-way split-K:
// wave w accumulates k in [w*8, w*8+8) of each BK=64 chunk).
// Same proven R1 inner loop (96 VGPR, no spill); the change is TLP:
// 16 waves/CU (4/SIMD) instead of 8 -> staging stalls of one block hide
// under the other block's FMA issue. Split-K partials reduced via a
// 3-round tree through 4 LDS regions (all barriers before any wave exits).
// ---------------------------------------------------------------------------
__global__ __launch_bounds__(512, 4) void moe_router_kernel(
    const float* __restrict__ x, const float* __restrict__ gw,
    float* __restrict__ out, float* __restrict__ meanacc)
{
    extern __shared__ float smem[];           // 4 x [64][68] regions (69632 B)
    float* const xs  = smem;                  // staging: x tile
    float* const wsh = smem + TILEF;          // staging: w tile

    const int t    = threadIdx.x;
    const int wave = t >> 6;       // 0..7
    const int lane = t & 63;
    const int tr   = lane >> 3;    // row group 0..7   (rows  tr + 8*i)
    const int tc   = lane & 7;     // expert group 0..7 (experts tc + 8*j)
    const int row0 = blockIdx.x * BM;

    // staging map: thread covers rows {strow, strow+32}, f4-col stcol
    const int strow = t >> 4;              // 0..31
    const int stcol = (t & 15) << 2;       // 0..60 step 4

    const float* xg = x  + (size_t)(row0 + strow) * DDIM + stcol;
    const float* wg = gw + (size_t)strow * DDIM + stcol;

    float acc[8][8];
    #pragma unroll
    for (int i = 0; i < 8; ++i)
        #pragma unroll
        for (int j = 0; j < 8; ++j) acc[i][j] = 0.0f;

    for (int k0 = 0; k0 < DDIM; k0 += BK) {
        // ---- stage x-tile [64][64] and w-tile [64][64] (2 f4 each) --------
        {
            float4 x0 = *reinterpret_cast<const float4*>(xg + k0);
            float4 x1 = *reinterpret_cast<const float4*>(xg + (size_t)32 * DDIM + k0);
            float4 w0 = *reinterpret_cast<const float4*>(wg + k0);
            float4 w1 = *reinterpret_cast<const float4*>(wg + (size_t)32 * DDIM + k0);
            *reinterpret_cast<float4*>(xs  + strow * LPAD + stcol)        = x0;
            *reinterpret_cast<float4*>(xs  + (strow + 32) * LPAD + stcol) = x1;
            *reinterpret_cast<float4*>(wsh + strow * LPAD + stcol)        = w0;
            *reinterpret_cast<float4*>(wsh + (strow + 32) * LPAD + stcol) = w1;
        }
        __syncthreads();
        // ---- compute this wave's K-slice (8 of the 64 k's) ----------------
        #pragma unroll
        for (int s2 = 0; s2 < 2; ++s2) {
            const int c = wave * 8 + s2 * 4;
            float4 xv[8], wv[8];
            #pragma unroll
            for (int i = 0; i < 8; ++i)
                xv[i] = *reinterpret_cast<const float4*>(xs + (tr + 8 * i) * LPAD + c);
            #pragma unroll
            for (int j = 0; j < 8; ++j)
                wv[j] = *reinterpret_cast<const float4*>(wsh + (tc + 8 * j) * LPAD + c);
            #pragma unroll
            for (int i = 0; i < 8; ++i)
                #pragma unroll
                for (int j = 0; j < 8; ++j) {
                    acc[i][j] += xv[i].x * wv[j].x;
                    acc[i][j] += xv[i].y * wv[j].y;
                    acc[i][j] += xv[i].z * wv[j].z;
                    acc[i][j] += xv[i].w * wv[j].w;
                }
        }
        __syncthreads();
    }

    // ---- 8 -> 1 split-K reduction: 3-round tree through 4 LDS regions -----
    // round 1: waves 4..7 write regions 0..3; waves 0..3 add
    if (wave >= 4) {
        float* r = smem + (wave - 4) * TILEF;
        #pragma unroll
        for (int i = 0; i < 8; ++i)
            #pragma unroll
            for (int j = 0; j < 8; ++j)
                r[(tr + 8 * i) * LPAD + tc + 8 * j] = acc[i][j];
    }
    __syncthreads();
    if (wave < 4) {
        const float* r = smem + wave * TILEF;
        #pragma unroll
        for (int i = 0; i < 8; ++i)
            #pragma unroll
            for (int j = 0; j < 8; ++j)
                acc[i][j] += r[(tr + 8 * i) * LPAD + tc + 8 * j];
    }
    __syncthreads();
    // round 2: waves 2,3 write regions 0,1; waves 0,1 add
    if (wave == 2 || wave == 3) {
        float* r = smem + (wave - 2) * TILEF;
        #pragma unroll
        for (int i = 0; i < 8; ++i)
            #pragma unroll
            for (int j = 0; j < 8; ++j)
                r[(tr + 8 * i) * LPAD + tc + 8 * j] = acc[i][j];
    }
    __syncthreads();
    if (wave < 2) {
        const float* r = smem + wave * TILEF;
        #pragma unroll
        for (int i = 0; i < 8; ++i)
            #pragma unroll
            for (int j = 0; j < 8; ++j)
                acc[i][j] += r[(tr + 8 * i) * LPAD + tc + 8 * j];
    }
    __syncthreads();
    // round 3: wave 1 writes region 0; wave 0 adds
    if (wave == 1) {
        float* r = smem;
        #pragma unroll
        for (int i = 0; i < 8; ++i)
            #pragma unroll
            for (int j = 0; j < 8; ++j)
                r[(tr + 8 * i) * LPAD + tc + 8 * j] = acc[i][j];
    }
    __syncthreads();

    if (wave != 0) return;   // all barriers done; wave 0 finishes alone

    {
        const float* r = smem;
        #pragma unroll
        for (int i = 0; i < 8; ++i)
            #pragma unroll
            for (int j = 0; j < 8; ++j)
                acc[i][j] += r[(tr + 8 * i) * LPAD + tc + 8 * j];
    }

    // ---- fused epilogue: softmax + top-2 + aux accumulation ---------------
    float auxacc[8];
    #pragma unroll
    for (int j = 0; j < 8; ++j) auxacc[j] = 0.0f;

    #pragma unroll
    for (int i = 0; i < 8; ++i) {
        // local stable top-2 over this lane's 8 experts
        float v1 = -3.4e38f, v2 = -3.4e38f;
        int   e1 = 1 << 30,  e2 = 1 << 30;
        #pragma unroll
        for (int j = 0; j < 8; ++j) {
            float v = acc[i][j];
            int   e = tc + 8 * j;
            if (v > v1 || (v == v1 && e < e1)) { v2 = v1; e2 = e1; v1 = v; e1 = e; }
            else if (v > v2 || (v == v2 && e < e2)) { v2 = v; e2 = e; }
        }
        // merge across the 8 lanes holding this row (stable, lower index wins)
        #pragma unroll
        for (int m = 1; m <= 4; m <<= 1) {
            float o1 = __shfl_xor(v1, m); int oe1 = __shfl_xor(e1, m);
            float o2 = __shfl_xor(v2, m); int oe2 = __shfl_xor(e2, m);
            bool aFirst = (v1 > o1) || (v1 == o1 && e1 < oe1);
            float n1, n2; int ne1, ne2;
            if (aFirst) {
                n1 = v1; ne1 = e1;
                bool sA = (v2 > o1) || (v2 == o1 && e2 < oe1);
                if (sA) { n2 = v2; ne2 = e2; } else { n2 = o1; ne2 = oe1; }
            } else {
                n1 = o1; ne1 = oe1;
                bool sB = (o2 > v1) || (o2 == v1 && oe2 < e1);
                if (sB) { n2 = o2; ne2 = oe2; } else { n2 = v1; ne2 = e1; }
            }
            v1 = n1; e1 = ne1; v2 = n2; e2 = ne2;
        }
        const float mx = v1;  // global row max

        float p[8];
        float sloc = 0.0f;
        #pragma unroll
        for (int j = 0; j < 8; ++j) { p[j] = expf(acc[i][j] - mx); sloc += p[j]; }
        float S = sloc;
        #pragma unroll
        for (int m = 1; m <= 4; m <<= 1) S += __shfl_xor(S, m);
        const float invS = 1.0f / S;

        const float p1 = expf(v1 - mx) * invS;   // = invS (v1 == mx)
        const float p2 = expf(v2 - mx) * invS;
        const float dn = p1 + p2 + EPSF;
        const float w1 = p1 / dn;
        const float w2 = p2 / dn;

        if (tc == 0) {
            const int r = row0 + tr + 8 * i;
            out[2 * r]                 = w1;
            out[2 * r + 1]             = w2;
            out[2 * NROWS + 2 * r]     = (float)e1;
            out[2 * NROWS + 2 * r + 1] = (float)e2;
        }
        #pragma unroll
        for (int j = 0; j < 8; ++j) auxacc[j] += p[j] * invS;
    }

    // reduce aux probs across the 8 row-groups (lanes differing in tr bits)
    #pragma unroll
    for (int m = 8; m <= 32; m <<= 1)
        #pragma unroll
        for (int j = 0; j < 8; ++j) auxacc[j] += __shfl_xor(auxacc[j], m);
    if (tr == 0) {
        #pragma unroll
        for (int j = 0; j < 8; ++j)
            atomicAdd(&meanacc[tc + 8 * j], auxacc[j]);
    }
}

__global__ void zero_ws_kernel(float* __restrict__ m)
{
    m[threadIdx.x] = 0.0f;
}

__global__ void aux_loss_kernel(const float* __restrict__ m,
                                float* __restrict__ out)
{
    const int e = threadIdx.x;           // 64 threads = 1 wave
    float mean = m[e] * (1.0f / (float)NROWS);
    float v = mean * logf(mean + EPSF);
    #pragma unroll
    for (int k = 1; k <= 32; k <<= 1) v += __shfl_xor(v, k);
    if (e == 0) out[4 * NROWS] = v;      // index 131072
}

extern "C" void kernel_launch(void* const* d_in, const int* in_sizes, int n_in,
                              void* d_out, int out_size, void* d_ws, size_t ws_size,
                              hipStream_t stream)
{
    const float* x   = (const float*)d_in[0];
    const float* gw  = (const float*)d_in[1];
    float* out       = (float*)d_out;
    float* meanacc   = (float*)d_ws;

    const size_t lds_bytes = 4 * TILEF * sizeof(float);   // 69632 B dynamic LDS

    hipLaunchKernelGGL(zero_ws_kernel, dim3(1), dim3(NEXP), 0, stream, meanacc);
    hipLaunchKernelGGL(moe_router_kernel, dim3(NROWS / BM), dim3(512), lds_bytes,
                       stream, x, gw, out, meanacc);
    hipLaunchKernelGGL(aux_loss_kernel, dim3(1), dim3(NEXP), 0, stream,
                       meanacc, out);
}